// Round 10
// baseline (21.547 us; speedup 1.0000x reference)
//
#include <hip/hip_runtime.h>

// ---------------------------------------------------------------------------
// FFT_Conv_Layer == 3x3 "same" spatial conv with flipped REAL filter plane:
//   out[b,o,y,x] = sum_{i,ky,kx} filts[0,i,o,ky,kx,0] * img[b,i,y+1-ky,x+1-kx]
//
// Ladder: R2 22.54 | R5 27.0 (1 wave/SIMD) | R7 21.24 (+XCD swz) |
//         R8 21.07 (stage order: neutral) | R9 21.10 (4 waves/SIMD: neutral)
// Diagnosis: all blocks run [stage burst][compute][write] IN PHASE grid-wide;
// throughput levers are neutral because phases serialize. R10: per-block
// cross-tile pipeline — block owns 4 rows = 2 tiles on a 6-slab LDS ring;
// tile-1's 2 new rows are reg-prefetched before tile-0 compute and ds-written
// after it (disjoint slots -> no extra barrier); tile-0 stores drain under
// tile-1 compute. Also cuts staged fetch 32->24 MB (6 rows/block vs 8).
// ---------------------------------------------------------------------------

typedef _Float16 f16x8 __attribute__((ext_vector_type(8)));
typedef float    f32x4 __attribute__((ext_vector_type(4)));

#define NB 16
#define NC 64
#define NH 64
#define NW 64
#define CHUNKS 528                 // 66 xp positions * 8 channel-chunks per slab
#define SLAB_BYTES (CHUNKS * 16)   // 8448 B per image row slab
#define WF_HALFS (9 * 2 * 4 * 64 * 8)  // taps * kc * n * lane * elem = 36864

// ---------------------------------------------------------------------------
// prep_w: filts [1][inC][outC][3][3][2] f32 -> per-fragment f16 weights
//   Wf[t][kc][n][lane][e] = filts[0][ i=kc*32+(l/16)*8+e ][ o=n*16+l%16 ][ky][kx][0]
// ---------------------------------------------------------------------------
__global__ __launch_bounds__(256) void prep_w(const float* __restrict__ filts,
                                              _Float16* __restrict__ wf) {
    const int f = blockIdx.x * 256 + threadIdx.x;
    if (f >= WF_HALFS) return;
    const int e  = f & 7;
    const int l  = (f >> 3) & 63;
    const int n  = (f >> 9) & 3;
    const int kc = (f >> 11) & 1;
    const int t  = f >> 12;              // 0..8
    const int i  = kc * 32 + (l >> 4) * 8 + e;
    const int o  = n * 16 + (l & 15);
    const int ky = t / 3, kx = t % 3;
    wf[f] = (_Float16)filts[(((i * 64 + o) * 3 + ky) * 3 + kx) * 2];
}

// ---------------------------------------------------------------------------
// conv_pipe: 256 blocks (XCD-swizzled) = (b, 4-row quad), 8 waves (512 thr).
//   6-slab ring covers image rows y0-1 .. y0+4. Tile t (rows y0+2t, y0+2t+1)
//   reads slots 2t .. 2t+3. Schedule:
//     stage slots 0-3 | issue pf loads (slots 4,5) | barrier |
//     compute t0 | cvt+ds_write slots 4,5 | barrier |
//     store t0 + compute t1 | store t1
//   Wave w: stage job (slab w>>1, half w&1); pf job (slab 4+(w>>2), qtr w&3);
//   compute (row w>>2, xh (w>>1)&1, oh w&1) -> 32x32 tile, 2x2 frags.
//   chunk = xp*8 + (ci^(xp&7)) swizzle -> conflict-free b128 LDS ops.
//   C/D layout (m89/m91-verified): o = n*16+(lane&15), x = m*16+(lane>>4)*4+j
// ---------------------------------------------------------------------------
__global__ __launch_bounds__(512, 2) void conv_pipe(const float* __restrict__ imgs,
                                                    const _Float16* __restrict__ wf,
                                                    float* __restrict__ out) {
    __shared__ uint4 ldsb[6 * SLAB_BYTES / 16];   // 50,688 B
    char* lds = reinterpret_cast<char*>(ldsb);
    // bijective XCD swizzle (256 = 8*32): XCD x gets swz in [32x, 32x+32)
    // = images {2x, 2x+1} -> staged row re-reads are XCD-local L2 hits.
    const int bid = blockIdx.x;
    const int swz = ((bid & 7) << 5) | (bid >> 3);
    const int b   = swz >> 4;
    const int y0  = (swz & 15) << 2;     // first of 4 output rows
    const int tid = threadIdx.x;
    const int w   = tid >> 6;            // wave 0..7
    const int l   = tid & 63;
    const int h   = l >> 4;              // k-chunk lane group
    const int r   = l & 15;              // A-row / B-col within fragment

    // ---- stage slots 0..3 (image rows y0-1 .. y0+2) ----
    {
        const int sl   = w >> 1;
        const int half = w & 1;
        const int y    = y0 - 1 + sl;
        const bool yv  = ((unsigned)y < (unsigned)NH);
        char* slab = lds + sl * SLAB_BYTES;

        if (half == 0 && l < 16) {       // 16 zero pad chunks (xp = 0, 65)
            const int ci  = l >> 1;
            const int xp2 = (l & 1) ? 65 : 0;
            const int c2  = xp2 * 8 + (ci ^ (xp2 & 7));
            f16x8 z;
            #pragma unroll
            for (int k = 0; k < 8; ++k) z[k] = (_Float16)0.f;
            *reinterpret_cast<f16x8*>(slab + c2 * 16) = z;
        }

        float f[32];
        if (yv) {
            const float* src = imgs + (((size_t)(b * NC + half * 32)) * NH + y) * NW + l;
            #pragma unroll
            for (int j = 0; j < 32; ++j) f[j] = src[(size_t)j * NH * NW];
        } else {
            #pragma unroll
            for (int j = 0; j < 32; ++j) f[j] = 0.f;
        }
        const int xp = l + 1;
        #pragma unroll
        for (int cj = 0; cj < 4; ++cj) {
            const int ci = half * 4 + cj;
            f16x8 v;
            #pragma unroll
            for (int k = 0; k < 8; ++k) v[k] = (_Float16)f[cj * 8 + k];
            const int chunk = xp * 8 + (ci ^ (xp & 7));
            *reinterpret_cast<f16x8*>(slab + chunk * 16) = v;
        }
    }

    // ---- issue prefetch loads for slots 4,5 (rows y0+3, y0+4) ----
    const int s2 = 4 + (w >> 2);         // slab 4..5
    const int q  = w & 3;                // channel quarter
    float pf[16];
    {
        const int y2 = y0 - 1 + s2;
        if ((unsigned)y2 < (unsigned)NH) {
            const float* src = imgs + (((size_t)(b * NC + q * 16)) * NH + y2) * NW + l;
            #pragma unroll
            for (int j = 0; j < 16; ++j) pf[j] = src[(size_t)j * NH * NW];
        } else {
            #pragma unroll
            for (int j = 0; j < 16; ++j) pf[j] = 0.f;
        }
    }
    __syncthreads();

    const int row = w >> 2;              // output row within tile
    const int xh  = (w >> 1) & 1;        // x half
    const int oh  = w & 1;               // outC half
    const int xbase = xh * 32 + r + 2;   // + (-kx) later

    // ---- compute tile 0 (slots row+2-ky in 0..3) ----
    f32x4 acc0[2][2];
    #pragma unroll
    for (int m = 0; m < 2; ++m)
        #pragma unroll
        for (int n = 0; n < 2; ++n) acc0[m][n] = f32x4{0.f, 0.f, 0.f, 0.f};

    #pragma unroll
    for (int ky = 0; ky < 3; ++ky) {
        const char* slab = lds + (row + 2 - ky) * SLAB_BYTES;
        #pragma unroll
        for (int kx = 0; kx < 3; ++kx) {
            const _Float16* wft = wf + (size_t)(ky * 3 + kx) * (2 * 4 * 64 * 8);
            #pragma unroll
            for (int kc = 0; kc < 2; ++kc) {
                f16x8 a[2], bb[2];
                #pragma unroll
                for (int m = 0; m < 2; ++m) {
                    const int xp = xbase + m * 16 - kx;
                    const int chunk = xp * 8 + (((kc << 2) + h) ^ (xp & 7));
                    a[m] = *reinterpret_cast<const f16x8*>(slab + chunk * 16);
                }
                #pragma unroll
                for (int n = 0; n < 2; ++n)
                    bb[n] = *reinterpret_cast<const f16x8*>(
                        wft + ((size_t)((kc << 2) + (oh * 2 + n)) * 64 + l) * 8);
                #pragma unroll
                for (int m = 0; m < 2; ++m)
                    #pragma unroll
                    for (int n = 0; n < 2; ++n)
                        acc0[m][n] = __builtin_amdgcn_mfma_f32_16x16x32_f16(a[m], bb[n], acc0[m][n], 0, 0, 0);
            }
        }
    }

    // ---- commit prefetch to slots 4,5 (disjoint from tile-0 reads) ----
    {
        char* slab = lds + s2 * SLAB_BYTES;
        if (q == 0 && l < 16) {
            const int ci  = l >> 1;
            const int xp2 = (l & 1) ? 65 : 0;
            const int c2  = xp2 * 8 + (ci ^ (xp2 & 7));
            f16x8 z;
            #pragma unroll
            for (int k = 0; k < 8; ++k) z[k] = (_Float16)0.f;
            *reinterpret_cast<f16x8*>(slab + c2 * 16) = z;
        }
        const int xp = l + 1;
        #pragma unroll
        for (int cj = 0; cj < 2; ++cj) {
            const int ci = q * 2 + cj;
            f16x8 v;
            #pragma unroll
            for (int k = 0; k < 8; ++k) v[k] = (_Float16)pf[cj * 8 + k];
            const int chunk = xp * 8 + (ci ^ (xp & 7));
            *reinterpret_cast<f16x8*>(slab + chunk * 16) = v;
        }
    }
    __syncthreads();

    // ---- store tile 0 (drains under tile-1 compute) ----
    {
        const int y = y0 + row;
        #pragma unroll
        for (int m = 0; m < 2; ++m) {
            const int x0 = xh * 32 + m * 16 + h * 4;
            #pragma unroll
            for (int n = 0; n < 2; ++n) {
                const int o = oh * 32 + n * 16 + r;
                *reinterpret_cast<f32x4*>(out + (((size_t)(b * 64 + o) * 64 + y) * 64) + x0) = acc0[m][n];
            }
        }
    }

    // ---- compute tile 1 (slots row+4-ky in 2..5) ----
    f32x4 acc1[2][2];
    #pragma unroll
    for (int m = 0; m < 2; ++m)
        #pragma unroll
        for (int n = 0; n < 2; ++n) acc1[m][n] = f32x4{0.f, 0.f, 0.f, 0.f};

    #pragma unroll
    for (int ky = 0; ky < 3; ++ky) {
        const char* slab = lds + (row + 4 - ky) * SLAB_BYTES;
        #pragma unroll
        for (int kx = 0; kx < 3; ++kx) {
            const _Float16* wft = wf + (size_t)(ky * 3 + kx) * (2 * 4 * 64 * 8);
            #pragma unroll
            for (int kc = 0; kc < 2; ++kc) {
                f16x8 a[2], bb[2];
                #pragma unroll
                for (int m = 0; m < 2; ++m) {
                    const int xp = xbase + m * 16 - kx;
                    const int chunk = xp * 8 + (((kc << 2) + h) ^ (xp & 7));
                    a[m] = *reinterpret_cast<const f16x8*>(slab + chunk * 16);
                }
                #pragma unroll
                for (int n = 0; n < 2; ++n)
                    bb[n] = *reinterpret_cast<const f16x8*>(
                        wft + ((size_t)((kc << 2) + (oh * 2 + n)) * 64 + l) * 8);
                #pragma unroll
                for (int m = 0; m < 2; ++m)
                    #pragma unroll
                    for (int n = 0; n < 2; ++n)
                        acc1[m][n] = __builtin_amdgcn_mfma_f32_16x16x32_f16(a[m], bb[n], acc1[m][n], 0, 0, 0);
            }
        }
    }

    {
        const int y = y0 + 2 + row;
        #pragma unroll
        for (int m = 0; m < 2; ++m) {
            const int x0 = xh * 32 + m * 16 + h * 4;
            #pragma unroll
            for (int n = 0; n < 2; ++n) {
                const int o = oh * 32 + n * 16 + r;
                *reinterpret_cast<f32x4*>(out + (((size_t)(b * 64 + o) * 64 + y) * 64) + x0) = acc1[m][n];
            }
        }
    }
}

extern "C" void kernel_launch(void* const* d_in, const int* in_sizes, int n_in,
                              void* d_out, int out_size, void* d_ws, size_t ws_size,
                              hipStream_t stream) {
    const float* imgs  = (const float*)d_in[0];   // [16][64][64][64] f32
    const float* filts = (const float*)d_in[1];   // [1][64][64][3][3][2] f32
    float* out = (float*)d_out;                   // [16][64][64][64] f32
    _Float16* wfb = (_Float16*)d_ws;              // 73,728 B only

    hipLaunchKernelGGL(prep_w, dim3((WF_HALFS + 255) / 256), dim3(256), 0, stream, filts, wfb);
    hipLaunchKernelGGL(conv_pipe, dim3(256), dim3(512), 0, stream, imgs, wfb, out);
}